// Round 4
// baseline (106.367 us; speedup 1.0000x reference)
//
#include <hip/hip_runtime.h>

#define EPS 1e-7f
#define LOG2E 1.44269504088896340736f

typedef float f32x2 __attribute__((ext_vector_type(2)));
typedef float f32x4 __attribute__((ext_vector_type(4)));

constexpr int BLOCK = 512;         // 8 waves/block, 2 blocks/CU
constexpr int JJ    = 4;           // lane-fast j slots
constexpr int JR    = 4;           // j's per thread -> 4 evals per LDS read
constexpr int JB    = JJ * JR;     // 16 outputs per block
constexpr int SS    = BLOCK / JJ;  // 128 i-segments per block
constexpr int CHUNK = 1024;        // points per LDS chunk
constexpr int PTS   = CHUNK / SS;  // 8 points per segment
constexpr int ROW   = 12;          // 12-float rows: 16B-aligned b128, uniform 2-way banks (free)
constexpr int REPS  = 4;           // DIAGNOSTIC: 4x N-sweep so kernel outranks the 39.5us fills
                                   // in rocprof top-5. n and d scale x4 -> n/(d+EPS) unchanged.

// Thread = (jj, ss). A wave has 16 distinct ss rows x 4-lane broadcast.
// SoA LDS: x,y,s,o arrays; compute reads 4 points per array as one
// ds_read_b128 (row starts 48B apart -> start banks {0,12,24,4,...}x2,
// every bank exactly 2-way = free per m136). Each b128 feeds 4 pts x 4 j
// = 16 evals -> LDS wave-instrs/CU/pass ~1024 x 12cyc ~5us (2.7x less
// than R3). Math: packed f32x2 FMA via __builtin_elementwise_fma.
__global__ __launch_bounds__(BLOCK, 4) void nw_block(
    const float2* __restrict__ x,        // M x 2 query points
    const float2* __restrict__ inputs,   // N x 2 data points
    const float*  __restrict__ outputs,  // N
    const float*  __restrict__ bw,       // M
    float*        __restrict__ out,      // M
    int N, int M)
{
    __shared__ __align__(16) float sX[SS][ROW];
    __shared__ __align__(16) float sY[SS][ROW];
    __shared__ __align__(16) float sS[SS][ROW];
    __shared__ __align__(16) float sO[SS][ROW];
    __shared__ float2 red[SS][JB];       // 16 KB

    const int tid = threadIdx.x;
    const int jj  = tid & (JJ - 1);
    const int ss  = tid >> 2;            // tid / JJ

    // per-thread coefficient pairs (splat): t = c0*s + c1*px + c2*py + c3, k<0 folded
    f32x2 c0p[JR], c1p[JR], c2p[JR], c3p[JR];
    #pragma unroll
    for (int r = 0; r < JR; ++r) {
        const int j = blockIdx.x * JB + jj + r * JJ;
        float k = 0.f, v1 = 0.f, v2 = 0.f, v3 = 0.f;
        if (j < M) {
            float2 xj = x[j];
            float  b  = bw[j];
            k  = -LOG2E / (2.0f * b * b);              // < 0
            v1 = -2.0f * k * xj.x;
            v2 = -2.0f * k * xj.y;
            v3 = k * fmaf(xj.x, xj.x, xj.y * xj.y);
        }
        c0p[r] = {k, k}; c1p[r] = {v1, v1}; c2p[r] = {v2, v2}; c3p[r] = {v3, v3};
    }

    f32x2 nump[JR], denp[JR];
    #pragma unroll
    for (int r = 0; r < JR; ++r) { nump[r] = {0.f, 0.f}; denp[r] = {0.f, 0.f}; }

    // register prefetch of chunk 0: thread t owns points (2t, 2t+1)
    const float4* in4  = (const float4*)inputs;   // 2 points per float4
    const float2* out2 = (const float2*)outputs;
    float4 pin  = make_float4(0.f, 0.f, 0.f, 0.f);
    float2 pout = make_float2(0.f, 0.f);
    if (2 * tid + 1 < N) { pin = in4[tid]; pout = out2[tid]; }

    for (int rep = 0; rep < REPS; ++rep) {
        for (int base = 0; base < N; base += CHUNK) {
            const int cnt = min(CHUNK, N - base);
            // stage pair (2t, 2t+1) -> row (2t)>>3, slots ((2t)&7, +1), b64 SoA writes
            {
                const int  r0 = tid >> 2;
                const int  s0 = (2 * tid) & (PTS - 1);
                const bool v0 = (2 * tid) < cnt;
                const bool v1 = (2 * tid + 1) < cnt;
                f32x2 xp = {v0 ? pin.x : 0.f, v1 ? pin.z : 0.f};
                f32x2 yp = {v0 ? pin.y : 0.f, v1 ? pin.w : 0.f};
                f32x2 sp = {v0 ? fmaf(pin.x, pin.x, pin.y * pin.y) : 3.0e38f,  // c0*s -> -inf -> w=0
                            v1 ? fmaf(pin.z, pin.z, pin.w * pin.w) : 3.0e38f};
                f32x2 op = {v0 ? pout.x : 0.f, v1 ? pout.y : 0.f};
                *(f32x2*)&sX[r0][s0] = xp;
                *(f32x2*)&sY[r0][s0] = yp;
                *(f32x2*)&sS[r0][s0] = sp;
                *(f32x2*)&sO[r0][s0] = op;
            }
            __syncthreads();

            // prefetch next chunk (wraps to chunk 0 across reps); flies under compute
            {
                int nb = base + CHUNK;
                if (nb >= N) nb = 0;
                const int i0 = (nb >> 1) + tid;
                if (2 * i0 + 1 < N) { pin = in4[i0]; pout = out2[i0]; }
            }

            // compute: PTS points as PTS/4 b128 groups x JR j's
            #pragma unroll
            for (int g = 0; g < PTS / 4; ++g) {
                f32x4 xq = *(const f32x4*)&sX[ss][4 * g];   // ds_read_b128, 2-way = free
                f32x4 yq = *(const f32x4*)&sY[ss][4 * g];
                f32x4 sq = *(const f32x4*)&sS[ss][4 * g];
                f32x4 oq = *(const f32x4*)&sO[ss][4 * g];
                f32x2 x0 = {xq.x, xq.y}, x1 = {xq.z, xq.w};
                f32x2 y0 = {yq.x, yq.y}, y1 = {yq.z, yq.w};
                f32x2 s0 = {sq.x, sq.y}, s1 = {sq.z, sq.w};
                f32x2 o0 = {oq.x, oq.y}, o1 = {oq.z, oq.w};
                #pragma unroll
                for (int r = 0; r < JR; ++r) {
                    f32x2 ta = __builtin_elementwise_fma(c2p[r], y0, c3p[r]);
                    ta = __builtin_elementwise_fma(c1p[r], x0, ta);
                    ta = __builtin_elementwise_fma(c0p[r], s0, ta);
                    f32x2 tb = __builtin_elementwise_fma(c2p[r], y1, c3p[r]);
                    tb = __builtin_elementwise_fma(c1p[r], x1, tb);
                    tb = __builtin_elementwise_fma(c0p[r], s1, tb);
                    f32x2 wa, wb;
                    wa.x = __builtin_amdgcn_exp2f(ta.x);
                    wa.y = __builtin_amdgcn_exp2f(ta.y);
                    wb.x = __builtin_amdgcn_exp2f(tb.x);
                    wb.y = __builtin_amdgcn_exp2f(tb.y);
                    nump[r] = __builtin_elementwise_fma(wa, o0, nump[r]);
                    nump[r] = __builtin_elementwise_fma(wb, o1, nump[r]);
                    denp[r] += wa + wb;
                }
            }
            __syncthreads();
        }
    }

    // two-stage block reduction across the 128 segments
    #pragma unroll
    for (int r = 0; r < JR; ++r)
        red[ss][jj + r * JJ] = make_float2(nump[r].x + nump[r].y,
                                           denp[r].x + denp[r].y);
    __syncthreads();
    if (tid < 16 * JB) {                 // 256 threads: (s2, slot)
        const int s2   = tid >> 4;       // 0..15
        const int slot = tid & 15;
        float n = 0.f, d = 0.f;
        #pragma unroll
        for (int k = 0; k < SS / 16; ++k) {
            n += red[s2 + 16 * k][slot].x;
            d += red[s2 + 16 * k][slot].y;
        }
        red[s2][slot] = make_float2(n, d);
    }
    __syncthreads();
    if (tid < JB) {
        float n = 0.f, d = 0.f;
        #pragma unroll
        for (int s = 0; s < 16; ++s) {
            n += red[s][tid].x;
            d += red[s][tid].y;
        }
        const int jo = blockIdx.x * JB + tid;
        if (jo < M) out[jo] = n / (d + EPS);
    }
}

extern "C" void kernel_launch(void* const* d_in, const int* in_sizes, int n_in,
                              void* d_out, int out_size, void* d_ws, size_t ws_size,
                              hipStream_t stream) {
    // setup_inputs() dict order: x (M*2), inputs (N*2), outputs (N), bandwidth (M)
    const float2* x       = (const float2*)d_in[0];
    const float2* inputs  = (const float2*)d_in[1];
    const float*  outputs = (const float*) d_in[2];
    const float*  bwv     = (const float*) d_in[3];
    const int N = in_sizes[2];   // outputs element count
    const int M = in_sizes[3];   // bandwidth element count
    float*        out     = (float*)d_out;

    dim3 grid((M + JB - 1) / JB);    // 512 blocks @ M=8192 -> 2 blocks/CU
    nw_block<<<grid, BLOCK, 0, stream>>>(x, inputs, outputs, bwv, out, N, M);
}

// Round 6
// 101.606 us; speedup vs baseline: 1.0469x; 1.0469x over previous
//
#include <hip/hip_runtime.h>

#define EPS 1e-7f
#define LOG2E 1.44269504088896340736f

typedef float f32x2 __attribute__((ext_vector_type(2)));

constexpr int BLOCK = 512;          // 8 waves
constexpr int PR    = 8;            // point-PAIRS per thread -> 16 points
constexpr int SEG   = BLOCK * PR * 2;  // 8192 points register-resident per block
constexpr int JT    = 8;            // outputs per block
constexpr int WAVES = BLOCK / 64;

// Inverted data flow vs R4: each thread holds 16 data points in REGISTERS
// (8 f32x2 pairs x {x,y,s,o} = 64 VGPR); the block sweeps its JT=8 outputs
// over them. Inner loop: 3 pk fma (affine t) + 2 exp + 1 pk fma + 1 pk add
// per 2 evals -- ZERO ds ops, ZERO barriers (R4 counters: LDS-read pipe
// ~14k cyc/CU/pass > trans floor 8.2k; barriers+stalls = 40% idle).
// Per-j accumulators (f32x2 x 8 x 2 = 32 VGPR) reduce once at the end via
// shfl-xor tree + 512B LDS. Grid = M/JT = 1024 blocks; ~16 waves/CU
// (VGPR-capped). Point loads redundant across blocks but L2-resident.
__global__ __launch_bounds__(BLOCK, 4) void nw_block(
    const float2* __restrict__ x,        // M x 2 query points
    const float2* __restrict__ inputs,   // N x 2 data points
    const float*  __restrict__ outputs,  // N
    const float*  __restrict__ bw,       // M
    float*        __restrict__ out,      // M
    int N, int M)
{
    __shared__ float2 red[WAVES][JT];    // 512 B

    const int tid  = threadIdx.x;
    const int wid  = tid >> 6;
    const int lane = tid & 63;
    const int j0   = blockIdx.x * JT;

    f32x2 nacc[JT], dacc[JT];
    #pragma unroll
    for (int jl = 0; jl < JT; ++jl) { nacc[jl] = {0.f, 0.f}; dacc[jl] = {0.f, 0.f}; }

    // outer segment loop: one iteration at N=8192; general N supported
    for (int s0 = 0; s0 < N; s0 += SEG) {
        // 16 points/thread into registers, pair (p, p+PR), stride-BLOCK coalesced
        f32x2 X2[PR], Y2[PR], S2[PR], O2[PR];
        #pragma unroll
        for (int p = 0; p < PR; ++p) {
            const int ia = s0 + p * BLOCK + tid;
            const int ib = s0 + (p + PR) * BLOCK + tid;
            float2 pa = make_float2(0.f, 0.f), pb = make_float2(0.f, 0.f);
            float  oa = 0.f, ob = 0.f, sa = 3.0e38f, sb = 3.0e38f;  // pad: k*s -> -inf -> w=0
            if (ia < N) { pa = inputs[ia]; oa = outputs[ia]; sa = fmaf(pa.x, pa.x, pa.y * pa.y); }
            if (ib < N) { pb = inputs[ib]; ob = outputs[ib]; sb = fmaf(pb.x, pb.x, pb.y * pb.y); }
            X2[p] = {pa.x, pb.x};
            Y2[p] = {pa.y, pb.y};
            S2[p] = {sa,   sb  };
            O2[p] = {oa,   ob  };
        }

        // sweep this block's JT outputs over the register-resident points
        #pragma unroll
        for (int jl = 0; jl < JT; ++jl) {
            const int j = j0 + jl;
            float k = 0.f, v1 = 0.f, v2 = 0.f, v3 = 0.f;
            if (j < M) {
                float2 xj = x[j];
                float  b  = bw[j];
                k  = -LOG2E / (2.0f * b * b);          // < 0
                v1 = -2.0f * k * xj.x;
                v2 = -2.0f * k * xj.y;
                v3 = k * fmaf(xj.x, xj.x, xj.y * xj.y);
            }
            const f32x2 C0 = {k, k}, C1 = {v1, v1}, C2 = {v2, v2}, C3 = {v3, v3};
            f32x2 n = nacc[jl], d = dacc[jl];
            #pragma unroll
            for (int p = 0; p < PR; ++p) {
                f32x2 t = __builtin_elementwise_fma(C2, Y2[p], C3);
                t = __builtin_elementwise_fma(C1, X2[p], t);
                t = __builtin_elementwise_fma(C0, S2[p], t);
                f32x2 w;
                w.x = __builtin_amdgcn_exp2f(t.x);
                w.y = __builtin_amdgcn_exp2f(t.y);
                n = __builtin_elementwise_fma(w, O2[p], n);
                d += w;
            }
            nacc[jl] = n; dacc[jl] = d;
        }
    }

    // reduction: pk-lane fold, shfl-xor tree over the wave, then cross-wave LDS
    #pragma unroll
    for (int jl = 0; jl < JT; ++jl) {
        float n = nacc[jl].x + nacc[jl].y;
        float d = dacc[jl].x + dacc[jl].y;
        #pragma unroll
        for (int off = 32; off; off >>= 1) {
            n += __shfl_xor(n, off);
            d += __shfl_xor(d, off);
        }
        if (lane == 0) red[wid][jl] = make_float2(n, d);
    }
    __syncthreads();
    if (tid < JT) {
        float n = 0.f, d = 0.f;
        #pragma unroll
        for (int w = 0; w < WAVES; ++w) {
            n += red[w][tid].x;
            d += red[w][tid].y;
        }
        const int j = j0 + tid;
        if (j < M) out[j] = n / (d + EPS);
    }
}

extern "C" void kernel_launch(void* const* d_in, const int* in_sizes, int n_in,
                              void* d_out, int out_size, void* d_ws, size_t ws_size,
                              hipStream_t stream) {
    // setup_inputs() dict order: x (M*2), inputs (N*2), outputs (N), bandwidth (M)
    const float2* x       = (const float2*)d_in[0];
    const float2* inputs  = (const float2*)d_in[1];
    const float*  outputs = (const float*) d_in[2];
    const float*  bwv     = (const float*) d_in[3];
    const int N = in_sizes[2];   // outputs element count
    const int M = in_sizes[3];   // bandwidth element count
    float*        out     = (float*)d_out;

    dim3 grid((M + JT - 1) / JT);    // 1024 blocks @ M=8192
    nw_block<<<grid, BLOCK, 0, stream>>>(x, inputs, outputs, bwv, out, N, M);
}

// Round 7
// 92.850 us; speedup vs baseline: 1.1456x; 1.0943x over previous
//
#include <hip/hip_runtime.h>

#define EPS 1e-7f
#define LOG2E 1.44269504088896340736f

typedef float f32x2 __attribute__((ext_vector_type(2)));

constexpr int BLOCK = 512;             // 8 waves
constexpr int PR    = 4;               // point-PAIRS per thread -> 8 points (32 VGPR)
constexpr int SEG   = BLOCK * PR * 2;  // 4096 points register-resident per segment
constexpr int JT    = 8;               // outputs per block
constexpr int WAVES = BLOCK / 64;

// R6 post-mortem: __launch_bounds__(512,4) capped VGPR at 64 (32 waves/CU
// interpretation) -> point arrays spilled to scratch (WRITE_SIZE 84 MB,
// VALUBusy 27%, 49us). Fix: (512,2) -> cap >=128, and PR 8->4 so demand
// (~32 pts + 32 acc + temps, coeffs in SGPR since j is block-uniform)
// fits comfortably. Structure unchanged: points in REGISTERS, zero LDS ops
// and zero barriers in the inner loop; block sweeps its JT=8 outputs over
// them; one shfl-tree + 512B LDS reduction at the end.
__global__ __launch_bounds__(BLOCK, 2) void nw_block(
    const float2* __restrict__ x,        // M x 2 query points
    const float2* __restrict__ inputs,   // N x 2 data points
    const float*  __restrict__ outputs,  // N
    const float*  __restrict__ bw,       // M
    float*        __restrict__ out,      // M
    int N, int M)
{
    __shared__ float2 red[WAVES][JT];    // 512 B

    const int tid  = threadIdx.x;
    const int wid  = tid >> 6;
    const int lane = tid & 63;
    const int j0   = blockIdx.x * JT;

    f32x2 nacc[JT], dacc[JT];
    #pragma unroll
    for (int jl = 0; jl < JT; ++jl) { nacc[jl] = {0.f, 0.f}; dacc[jl] = {0.f, 0.f}; }

    for (int s0 = 0; s0 < N; s0 += SEG) {
        // 8 points/thread into registers, pair (p, p+PR), stride-BLOCK coalesced
        f32x2 X2[PR], Y2[PR], S2[PR], O2[PR];
        #pragma unroll
        for (int p = 0; p < PR; ++p) {
            const int ia = s0 + p * BLOCK + tid;
            const int ib = s0 + (p + PR) * BLOCK + tid;
            float2 pa = make_float2(0.f, 0.f), pb = make_float2(0.f, 0.f);
            float  oa = 0.f, ob = 0.f, sa = 3.0e38f, sb = 3.0e38f;  // pad: k*s -> -inf -> w=0
            if (ia < N) { pa = inputs[ia]; oa = outputs[ia]; sa = fmaf(pa.x, pa.x, pa.y * pa.y); }
            if (ib < N) { pb = inputs[ib]; ob = outputs[ib]; sb = fmaf(pb.x, pb.x, pb.y * pb.y); }
            X2[p] = {pa.x, pb.x};
            Y2[p] = {pa.y, pb.y};
            S2[p] = {sa,   sb  };
            O2[p] = {oa,   ob  };
        }

        // sweep this block's JT outputs over the register-resident points
        #pragma unroll
        for (int jl = 0; jl < JT; ++jl) {
            const int j = j0 + jl;           // block-uniform -> scalar loads / SGPR coeffs
            float k = 0.f, v1 = 0.f, v2 = 0.f, v3 = 0.f;
            if (j < M) {
                float2 xj = x[j];
                float  b  = bw[j];
                k  = -LOG2E / (2.0f * b * b);          // < 0
                v1 = -2.0f * k * xj.x;
                v2 = -2.0f * k * xj.y;
                v3 = k * fmaf(xj.x, xj.x, xj.y * xj.y);
            }
            const f32x2 C0 = {k, k}, C1 = {v1, v1}, C2 = {v2, v2}, C3 = {v3, v3};
            f32x2 n = nacc[jl], d = dacc[jl];
            #pragma unroll
            for (int p = 0; p < PR; ++p) {
                f32x2 t = __builtin_elementwise_fma(C2, Y2[p], C3);
                t = __builtin_elementwise_fma(C1, X2[p], t);
                t = __builtin_elementwise_fma(C0, S2[p], t);
                f32x2 w;
                w.x = __builtin_amdgcn_exp2f(t.x);
                w.y = __builtin_amdgcn_exp2f(t.y);
                n = __builtin_elementwise_fma(w, O2[p], n);
                d += w;
            }
            nacc[jl] = n; dacc[jl] = d;
        }
    }

    // reduction: pk-lane fold, shfl-xor tree over the wave, then cross-wave LDS
    #pragma unroll
    for (int jl = 0; jl < JT; ++jl) {
        float n = nacc[jl].x + nacc[jl].y;
        float d = dacc[jl].x + dacc[jl].y;
        #pragma unroll
        for (int off = 32; off; off >>= 1) {
            n += __shfl_xor(n, off);
            d += __shfl_xor(d, off);
        }
        if (lane == 0) red[wid][jl] = make_float2(n, d);
    }
    __syncthreads();
    if (tid < JT) {
        float n = 0.f, d = 0.f;
        #pragma unroll
        for (int w = 0; w < WAVES; ++w) {
            n += red[w][tid].x;
            d += red[w][tid].y;
        }
        const int j = j0 + tid;
        if (j < M) out[j] = n / (d + EPS);
    }
}

extern "C" void kernel_launch(void* const* d_in, const int* in_sizes, int n_in,
                              void* d_out, int out_size, void* d_ws, size_t ws_size,
                              hipStream_t stream) {
    // setup_inputs() dict order: x (M*2), inputs (N*2), outputs (N), bandwidth (M)
    const float2* x       = (const float2*)d_in[0];
    const float2* inputs  = (const float2*)d_in[1];
    const float*  outputs = (const float*) d_in[2];
    const float*  bwv     = (const float*) d_in[3];
    const int N = in_sizes[2];   // outputs element count
    const int M = in_sizes[3];   // bandwidth element count
    float*        out     = (float*)d_out;

    dim3 grid((M + JT - 1) / JT);    // 1024 blocks @ M=8192
    nw_block<<<grid, BLOCK, 0, stream>>>(x, inputs, outputs, bwv, out, N, M);
}

// Round 8
// 72.937 us; speedup vs baseline: 1.4583x; 1.2730x over previous
//
#include <hip/hip_runtime.h>

#define EPS 1e-7f
#define LOG2E 1.44269504088896340736f

typedef float f32x2 __attribute__((ext_vector_type(2)));
typedef float f32x4 __attribute__((ext_vector_type(4)));

constexpr int BLOCK = 1024;          // 16 waves, 1 block/CU (LDS-capped)
constexpr int JJ    = 8;             // lane-fast j slots
constexpr int JR    = 4;             // j's per thread
constexpr int JB    = JJ * JR;       // 32 outputs per block
constexpr int SS    = BLOCK / JJ;    // 128 i-segments
constexpr int SEGN  = 8192;          // points LDS-resident per pass (= N here)
constexpr int PTS   = SEGN / SS;     // 64 points per segment
constexpr int ROW   = PTS + 4;       // 68: rows 16B-aligned; ss->bank 4*ss%32, conflict-free b128

// Whole-N LDS residency: all 8192 points staged ONCE into SoA LDS (139 KB),
// then the main sweep has ZERO barriers and ZERO re-staging (R4's 16
// barriers/pass + per-chunk stage are gone). Thread (jj,ss) sweeps its 64
// points x 4 register j's = 256 evals; packed f32x2 math = ~13 issue
// cyc/wave-eval; ds_read_b128 conflict-free by ROW=68 padding. Amortization
// lesson from R7: evals/thread/overhead is what matters -- here coeff setup
// (4 j) + reduction happen once against 256 evals.
__global__ __launch_bounds__(BLOCK, 4) void nw_block(
    const float2* __restrict__ x,        // M x 2 query points
    const float2* __restrict__ inputs,   // N x 2 data points
    const float*  __restrict__ outputs,  // N
    const float*  __restrict__ bw,       // M
    float*        __restrict__ out,      // M
    int N, int M)
{
    __shared__ float sA[4][SS][ROW];     // x,y,s,o: 4*128*68*4B = 139.3 KB

    const int tid = threadIdx.x;
    const int jj  = tid & (JJ - 1);
    const int ss  = tid >> 3;
    const int j0  = blockIdx.x * JB;

    // per-thread coefficient pairs (splat): t = c0*s + c1*px + c2*py + c3, k<0 folded
    f32x2 c0p[JR], c1p[JR], c2p[JR], c3p[JR];
    #pragma unroll
    for (int r = 0; r < JR; ++r) {
        const int j = j0 + jj + r * JJ;
        float k = 0.f, v1 = 0.f, v2 = 0.f, v3 = 0.f;
        if (j < M) {
            float2 xj = x[j];
            float  b  = bw[j];
            k  = -LOG2E / (2.0f * b * b);              // < 0 (b >= 0.5)
            v1 = -2.0f * k * xj.x;
            v2 = -2.0f * k * xj.y;
            v3 = k * fmaf(xj.x, xj.x, xj.y * xj.y);
        }
        c0p[r] = {k, k}; c1p[r] = {v1, v1}; c2p[r] = {v2, v2}; c3p[r] = {v3, v3};
    }

    f32x2 nump[JR], denp[JR];
    #pragma unroll
    for (int r = 0; r < JR; ++r) { nump[r] = {0.f, 0.f}; denp[r] = {0.f, 0.f}; }

    for (int s0 = 0; s0 < N; s0 += SEGN) {
        // stage SEGN points: thread handles i = tid + k*BLOCK (coalesced global,
        // conflict-free LDS writes: consecutive lanes -> consecutive banks)
        #pragma unroll
        for (int k = 0; k < SEGN / BLOCK; ++k) {
            const int i  = tid + k * BLOCK;
            const int gi = s0 + i;
            float2 p = make_float2(0.f, 0.f);
            float  o = 0.f, s = 3.0e38f;              // pad: k*s -> -inf -> w = 0
            if (gi < N) { p = inputs[gi]; o = outputs[gi]; s = fmaf(p.x, p.x, p.y * p.y); }
            const int r = i >> 6;                     // i / PTS
            const int c = i & (PTS - 1);
            sA[0][r][c] = p.x;
            sA[1][r][c] = p.y;
            sA[2][r][c] = s;
            sA[3][r][c] = o;
        }
        __syncthreads();

        // main sweep: 16 groups of 4 points, zero barriers
        #pragma unroll 4
        for (int g = 0; g < PTS / 4; ++g) {
            f32x4 xq = *(const f32x4*)&sA[0][ss][4 * g];   // ds_read_b128, conflict-free
            f32x4 yq = *(const f32x4*)&sA[1][ss][4 * g];
            f32x4 sq = *(const f32x4*)&sA[2][ss][4 * g];
            f32x4 oq = *(const f32x4*)&sA[3][ss][4 * g];
            f32x2 x0 = {xq.x, xq.y}, x1 = {xq.z, xq.w};
            f32x2 y0 = {yq.x, yq.y}, y1 = {yq.z, yq.w};
            f32x2 s0p = {sq.x, sq.y}, s1p = {sq.z, sq.w};
            f32x2 o0 = {oq.x, oq.y}, o1 = {oq.z, oq.w};
            #pragma unroll
            for (int r = 0; r < JR; ++r) {
                f32x2 ta = __builtin_elementwise_fma(c2p[r], y0, c3p[r]);
                ta = __builtin_elementwise_fma(c1p[r], x0, ta);
                ta = __builtin_elementwise_fma(c0p[r], s0p, ta);
                f32x2 tb = __builtin_elementwise_fma(c2p[r], y1, c3p[r]);
                tb = __builtin_elementwise_fma(c1p[r], x1, tb);
                tb = __builtin_elementwise_fma(c0p[r], s1p, tb);
                f32x2 wa, wb;
                wa.x = __builtin_amdgcn_exp2f(ta.x);
                wa.y = __builtin_amdgcn_exp2f(ta.y);
                wb.x = __builtin_amdgcn_exp2f(tb.x);
                wb.y = __builtin_amdgcn_exp2f(tb.y);
                nump[r] = __builtin_elementwise_fma(wa, o0, nump[r]);
                nump[r] = __builtin_elementwise_fma(wb, o1, nump[r]);
                denp[r] += wa + wb;
            }
        }
        __syncthreads();   // points no longer needed (next pass overwrites / reduction aliases)
    }

    // reduction: alias red[SS][JB] (32 KB) into sA -- safe after trailing barrier
    float2 (*red)[JB] = (float2 (*)[JB]) & sA[0][0][0];
    #pragma unroll
    for (int r = 0; r < JR; ++r)
        red[ss][jj + r * JJ] = make_float2(nump[r].x + nump[r].y,
                                           denp[r].x + denp[r].y);
    __syncthreads();
    if (tid < 16 * JB) {                 // 512 threads: (s2 in 0..15, slot in 0..31)
        const int s2   = tid >> 5;
        const int slot = tid & (JB - 1);
        float n = 0.f, d = 0.f;
        #pragma unroll
        for (int k = 0; k < SS / 16; ++k) {   // rows s2 + 16k (reads own write slot only)
            n += red[s2 + 16 * k][slot].x;
            d += red[s2 + 16 * k][slot].y;
        }
        red[s2][slot] = make_float2(n, d);
    }
    __syncthreads();
    if (tid < JB) {
        float n = 0.f, d = 0.f;
        #pragma unroll
        for (int s = 0; s < 16; ++s) {
            n += red[s][tid].x;
            d += red[s][tid].y;
        }
        const int j = j0 + tid;
        if (j < M) out[j] = n / (d + EPS);
    }
}

extern "C" void kernel_launch(void* const* d_in, const int* in_sizes, int n_in,
                              void* d_out, int out_size, void* d_ws, size_t ws_size,
                              hipStream_t stream) {
    // setup_inputs() dict order: x (M*2), inputs (N*2), outputs (N), bandwidth (M)
    const float2* x       = (const float2*)d_in[0];
    const float2* inputs  = (const float2*)d_in[1];
    const float*  outputs = (const float*) d_in[2];
    const float*  bwv     = (const float*) d_in[3];
    const int N = in_sizes[2];   // outputs element count
    const int M = in_sizes[3];   // bandwidth element count
    float*        out     = (float*)d_out;

    dim3 grid((M + JB - 1) / JB);    // 256 blocks @ M=8192 -> 1 block/CU
    nw_block<<<grid, BLOCK, 0, stream>>>(x, inputs, outputs, bwv, out, N, M);
}